// Round 19
// baseline (359.508 us; speedup 1.0000x reference)
//
#include <hip/hip_runtime.h>
#include <hip/hip_bf16.h>
#include <stdint.h>

// Problem constants (B=2, T=2048, D=1024, F=4096, E=8)
#define N_TOK 4096      // B*T
#define D_DIM 1024
#define F_DIM 4096
#define E_NUM 8

typedef unsigned short u16;
typedef __attribute__((ext_vector_type(8))) short short8;   // 8 bf16 (4 VGPRs)
typedef __attribute__((ext_vector_type(4))) float f32x4;

__device__ __forceinline__ u16 f2bf(float f) {
  union { float f; uint32_t u; } v; v.f = f;
  uint32_t u = v.u;
  uint32_t r = (u + 0x7FFFu + ((u >> 16) & 1u)) >> 16;
  return (u16)r;
}

__device__ __forceinline__ void gld_lds16(const u16* g, u16* l) {
  // async global->LDS, 16B per lane; LDS dest = wave-uniform base + lane*16
  __builtin_amdgcn_global_load_lds(
      (const __attribute__((address_space(1))) uint32_t*)g,
      (__attribute__((address_space(3))) uint32_t*)l, 16, 0, 0);
}

// ---- merged transpose+convert: W1 [E][D][F] -> w1t [E][F][D], W2 likewise ----
// One launch, 16384 blocks: [0,8192) = W1, [8192,16384) = W2. 64x64 tiles.
__global__ __launch_bounds__(256) void transpose_cvt2_kernel(
    const float* __restrict__ W1, const float* __restrict__ W2,
    u16* __restrict__ w1t, u16* __restrict__ w2t) {
  __shared__ u16 tile[64][72];   // pad 72: 144B row stride
  int bid = blockIdx.x;
  const float* src; u16* dst; int R, C, bx, by, e;
  if (bid < 8192) {
    int s = bid; bx = s & 63; by = (s >> 6) & 15; e = s >> 10;
    R = D_DIM; C = F_DIM;
    src = W1 + (size_t)e * R * C; dst = w1t + (size_t)e * R * C;
  } else {
    int s = bid - 8192; bx = s & 15; by = (s >> 4) & 63; e = s >> 10;
    R = F_DIM; C = D_DIM;
    src = W2 + (size_t)e * R * C; dst = w2t + (size_t)e * R * C;
  }
  int r0 = by * 64, c0 = bx * 64;
  int tid = threadIdx.x;
  int lr = tid & 15;    // 16 lanes cover 64 elems
  int rr = tid >> 4;    // 16 rows / pass
#pragma unroll
  for (int p = 0; p < 4; ++p) {
    int r = rr + p * 16;
    float4 v = *(const float4*)&src[(size_t)(r0 + r) * C + c0 + lr * 4];
    tile[lr * 4 + 0][r] = f2bf(v.x);
    tile[lr * 4 + 1][r] = f2bf(v.y);
    tile[lr * 4 + 2][r] = f2bf(v.z);
    tile[lr * 4 + 3][r] = f2bf(v.w);
  }
  __syncthreads();
#pragma unroll
  for (int p = 0; p < 4; ++p) {
    int c = rr + p * 16;
    ushort4 o = *(const ushort4*)&tile[c][lr * 4];
    *(ushort4*)&dst[(size_t)(c0 + c) * R + r0 + lr * 4] = o;
  }
}

// -------- gate: logits, top-2, softmax + fused x->bf16 convert (NO atomics) --------
__global__ void gate_kernel(const float* __restrict__ x, const float* __restrict__ Wg,
                            u16* __restrict__ xb, int2* __restrict__ choice,
                            float* __restrict__ sc2) {
  int n = blockIdx.x;
  int l = threadIdx.x;  // 64
  const float* xr = x + (size_t)n * D_DIM;
  u16* xbr = xb + (size_t)n * D_DIM;
  float acc[E_NUM];
#pragma unroll
  for (int e = 0; e < E_NUM; ++e) acc[e] = 0.f;
  for (int d = l; d < D_DIM; d += 64) {
    float xv = xr[d];
    xbr[d] = f2bf(xv);          // fused convert (coalesced 2B/lane)
#pragma unroll
    for (int e = 0; e < E_NUM; ++e) acc[e] += xv * Wg[e * D_DIM + d];
  }
#pragma unroll
  for (int e = 0; e < E_NUM; ++e) {
    float v = acc[e];
#pragma unroll
    for (int off = 32; off > 0; off >>= 1) v += __shfl_xor(v, off);
    acc[e] = v;
  }
  if (l == 0) {
    int i0 = 0; float m0 = acc[0];
#pragma unroll
    for (int e = 1; e < E_NUM; ++e) if (acc[e] > m0) { m0 = acc[e]; i0 = e; }
    int i1 = -1; float m1 = -INFINITY;
#pragma unroll
    for (int e = 0; e < E_NUM; ++e) if (e != i0 && acc[e] > m1) { m1 = acc[e]; i1 = e; }
    float z = __expf(m1 - m0);
    float s0 = 1.f / (1.f + z);
    sc2[n * 2 + 0] = s0;
    sc2[n * 2 + 1] = 1.f - s0;
    choice[n] = make_int2(i0, i1);
  }
}

// ---------------- route: deterministic ballot-prefix compaction ----------------
__global__ void route_kernel(const int2* __restrict__ choice, int* __restrict__ cnt,
                             int* __restrict__ tok_list) {
  int e = blockIdx.x;
  int l = threadIdx.x;  // 64
  unsigned long long below = (l == 0) ? 0ull : ((~0ull) >> (64 - l));
  int c = 0;
  for (int it = 0; it < N_TOK / 64; ++it) {
    int n = it * 64 + l;
    int2 ch = choice[n];
    unsigned long long b0 = __ballot(ch.x == e);
    if (ch.x == e) tok_list[e * N_TOK + c + __popcll(b0 & below)] = 2 * n;
    c += __popcll(b0);
    unsigned long long b1 = __ballot(ch.y == e);
    if (ch.y == e) tok_list[e * N_TOK + c + __popcll(b1 & below)] = 2 * n + 1;
    c += __popcll(b1);
  }
  if (l == 0) cnt[e] = c;
}

__global__ void prefix_kernel(const int* __restrict__ cnt, int* __restrict__ base) {
  if (threadIdx.x == 0) {
    int s = 0;
    for (int e = 0; e < E_NUM; ++e) { base[e] = s; s += cnt[e]; }
  }
}

// ---------------- up GEMM: act[be+i][f] = silu( x[tok_i] @ W1[e] ) ----------------
// r18 config: 128x128, BK=32, 8 waves (2M x 4N, acc[4][2]), dbuf, counted
// vmcnt(2), raw barriers. Grid 8192 -> 4 blocks/CU. XCD-chunked q=1024.
__global__ __launch_bounds__(512) void up_gemm(
    const u16* __restrict__ xb, const u16* __restrict__ w1t,
    const int* __restrict__ cnt, const int* __restrict__ base,
    const int* __restrict__ tok_list, u16* __restrict__ act) {
  __shared__ u16 As[2][128 * 32];
  __shared__ u16 Bs[2][128 * 32];

  const int bid = blockIdx.x;
  const int orig = (bid & 7) * 1024 + (bid >> 3);   // bijective: 8192 % 8 == 0
  const int bx = orig & 31, by = (orig >> 5) & 31, e = orig >> 10;

  const int ce = cnt[e];
  const int row0 = by * 128;
  if (row0 >= ce) return;
  const int col0 = bx * 128;
  const int be = base[e];

  const int tid = threadIdx.x;
  const int wave = tid >> 6, lane = tid & 63;
  const int wm = wave >> 2, wn = wave & 3;          // 2M x 4N
  const int lr = lane & 15, kq = lane >> 4;

  const int rsA = wave * 16 + (lane >> 2);          // one 16-row segment per wave
  const int kb = (((lane & 3) ^ ((lane >> 3) & 3)) * 8);  // swizzled write k-offset
  const int kq8 = ((kq ^ ((lr >> 1) & 3)) * 8);           // swizzled read k-offset

  int ga = row0 + rsA;
  int e0 = (ga < ce) ? (tok_list[e * N_TOK + ga] & (2 * N_TOK - 1)) : 0;
  const u16* srcA = xb + (e0 >> 1) * D_DIM + kb;
  const u16* srcB = w1t + (size_t)(e * F_DIM + col0 + rsA) * D_DIM + kb;

  f32x4 acc[4][2];
#pragma unroll
  for (int m = 0; m < 4; ++m)
#pragma unroll
    for (int n = 0; n < 2; ++n) acc[m][n] = (f32x4){0.f, 0.f, 0.f, 0.f};

#define USTAGE(k0, b)                              \
  do {                                             \
    gld_lds16(srcA + (k0), &As[b][wave * 512]);    \
    gld_lds16(srcB + (k0), &Bs[b][wave * 512]);    \
  } while (0)

#define UCOMPUTE(b)                                                           \
  do {                                                                        \
    short8 a[4], bb[2];                                                       \
    _Pragma("unroll") for (int m = 0; m < 4; ++m)                             \
        a[m] = *(const short8*)&As[b][(wm * 64 + m * 16 + lr) * 32 + kq8];    \
    _Pragma("unroll") for (int n = 0; n < 2; ++n)                             \
        bb[n] = *(const short8*)&Bs[b][(wn * 32 + n * 16 + lr) * 32 + kq8];   \
    _Pragma("unroll") for (int m = 0; m < 4; ++m)                             \
        _Pragma("unroll") for (int n = 0; n < 2; ++n)                         \
            acc[m][n] = __builtin_amdgcn_mfma_f32_16x16x32_bf16(a[m], bb[n], acc[m][n], 0, 0, 0); \
  } while (0)

  const int NT = D_DIM / 32;   // 32 K-steps
  USTAGE(0, 0);
  USTAGE(32, 1);
  asm volatile("s_waitcnt vmcnt(2)" ::: "memory");
  __builtin_amdgcn_s_barrier();
  __builtin_amdgcn_sched_barrier(0);
  int cur = 0;
  for (int t = 0; t < NT; ++t) {
    UCOMPUTE(cur);
    __builtin_amdgcn_sched_barrier(0);
    __builtin_amdgcn_s_barrier();
    __builtin_amdgcn_sched_barrier(0);
    if (t + 2 < NT) {
      USTAGE((t + 2) * 32, cur);
      asm volatile("s_waitcnt vmcnt(2)" ::: "memory");
    } else {
      asm volatile("s_waitcnt vmcnt(0)" ::: "memory");
    }
    __builtin_amdgcn_s_barrier();
    __builtin_amdgcn_sched_barrier(0);
    cur ^= 1;
  }
#undef USTAGE
#undef UCOMPUTE

  // epilogue: silu (native exp) -> bf16 act
#pragma unroll
  for (int m = 0; m < 4; ++m) {
#pragma unroll
    for (int rg = 0; rg < 4; ++rg) {
      int row = wm * 64 + m * 16 + kq * 4 + rg;
      int i = row0 + row;
      if (i < ce) {
        u16* dst = act + (size_t)(be + i) * F_DIM + col0 + wn * 32;
#pragma unroll
        for (int n = 0; n < 2; ++n) {
          float v = acc[m][n][rg];
          float s = v / (1.f + __expf(-v));
          dst[n * 16 + lr] = f2bf(s);
        }
      }
    }
  }
}

// ---------------- down GEMM: out[tok] += score * ( act_row @ W2[e] ) ----------------
// NEW cell: 128x128, BK=64, 8 waves, dbuf (64 KB -> still 2 blocks/CU,
// 16 waves/CU — occupancy identical to r13) — halves barrier-triples
// (128->64) and doubles MFMA cover per barrier (8->16). Addressing = r14's
// refcheck-verified 128B-row swizzle: write kslot=(lane&7)^(lane>>3),
// read ks=((kk*4+kq)^(lr&7)). Skeleton = r13's race-verified loop, vmcnt 4.
// Grid 2048 (8x * 32y * 8e), XCD-chunked q=256.
__global__ __launch_bounds__(512) void down_gemm(
    const u16* __restrict__ act, const u16* __restrict__ w2t,
    const int* __restrict__ cnt, const int* __restrict__ base,
    const int* __restrict__ tok_list, const float* __restrict__ sc2,
    float* __restrict__ out) {
  __shared__ u16 As[2][128 * 64];   // 16 KB per buf
  __shared__ u16 Bs[2][128 * 64];
  __shared__ int toks[128];

  const int bid = blockIdx.x;
  const int orig = (bid & 7) * 256 + (bid >> 3);    // bijective: 2048 % 8 == 0
  const int bx = orig & 7, by = (orig >> 3) & 31, e = orig >> 8;

  const int ce = cnt[e];
  const int row0 = by * 128;
  if (row0 >= ce) return;
  const int col0 = bx * 128;
  const int be = base[e];

  const int tid = threadIdx.x;
  const int wave = tid >> 6, lane = tid & 63;
  const int wm = wave >> 2, wn = wave & 3;          // 2M x 4N
  const int lr = lane & 15, kq = lane >> 4;

  if (tid < 128) {
    int i = row0 + tid;
    toks[tid] = (i < ce) ? tok_list[e * N_TOK + i] : -1;
  }
  __syncthreads();   // toks visible before raw-barrier loop

  // staging: seg = 8 rows x 64k (1 KB); lane covers row seg*8+(lane>>3),
  // k-slot (lane&7)^(lane>>3). Read side XORs the same involution.
  const int srow = lane >> 3;
  const int kb = ((lane & 7) ^ srow) * 8;           // swizzled write k-offset (elems)
  const int rsw = lr & 7;                           // read-side row&7

  const u16* srcA[2];                               // A rows wave*16 + j*8 + srow
#pragma unroll
  for (int j = 0; j < 2; ++j) {
    int ra = min(be + row0 + wave * 16 + j * 8 + srow, 2 * N_TOK - 1);
    srcA[j] = act + (size_t)ra * F_DIM + kb;
  }
  const u16* srcB[2];                               // B rows wave*16 + j*8 + srow
#pragma unroll
  for (int j = 0; j < 2; ++j) {
    int rb = e * D_DIM + col0 + wave * 16 + j * 8 + srow;
    srcB[j] = w2t + (size_t)rb * F_DIM + kb;
  }

  f32x4 acc[4][2];
#pragma unroll
  for (int m = 0; m < 4; ++m)
#pragma unroll
    for (int n = 0; n < 2; ++n) acc[m][n] = (f32x4){0.f, 0.f, 0.f, 0.f};

#define DSTAGE(k0, b)                                              \
  do {                                                             \
    gld_lds16(srcA[0] + (k0), &As[b][(wave * 2 + 0) * 512]);       \
    gld_lds16(srcA[1] + (k0), &As[b][(wave * 2 + 1) * 512]);       \
    gld_lds16(srcB[0] + (k0), &Bs[b][(wave * 2 + 0) * 512]);       \
    gld_lds16(srcB[1] + (k0), &Bs[b][(wave * 2 + 1) * 512]);       \
  } while (0)

#define DCOMPUTE(b)                                                             \
  do {                                                                          \
    _Pragma("unroll") for (int kk = 0; kk < 2; ++kk) {                          \
      const int ks = ((kk * 4 + kq) ^ rsw) * 8;                                 \
      short8 a[4], bb[2];                                                       \
      _Pragma("unroll") for (int m = 0; m < 4; ++m)                             \
          a[m] = *(const short8*)&As[b][(wm * 64 + m * 16 + lr) * 64 + ks];     \
      _Pragma("unroll") for (int n = 0; n < 2; ++n)                             \
          bb[n] = *(const short8*)&Bs[b][(wn * 32 + n * 16 + lr) * 64 + ks];    \
      _Pragma("unroll") for (int m = 0; m < 4; ++m)                             \
          _Pragma("unroll") for (int n = 0; n < 2; ++n)                         \
              acc[m][n] = __builtin_amdgcn_mfma_f32_16x16x32_bf16(a[m], bb[n], acc[m][n], 0, 0, 0); \
    }                                                                           \
  } while (0)

  const int NT = F_DIM / 64;   // 64 K-steps
  DSTAGE(0, 0);
  DSTAGE(64, 1);
  asm volatile("s_waitcnt vmcnt(4)" ::: "memory");   // stage0 landed (per-wave)
  __builtin_amdgcn_s_barrier();
  __builtin_amdgcn_sched_barrier(0);
  int cur = 0;
  for (int t = 0; t < NT; ++t) {
    DCOMPUTE(cur);
    __builtin_amdgcn_sched_barrier(0);
    __builtin_amdgcn_s_barrier();   // all readers done with buf cur
    __builtin_amdgcn_sched_barrier(0);
    if (t + 2 < NT) {
      DSTAGE((t + 2) * 64, cur);
      asm volatile("s_waitcnt vmcnt(4)" ::: "memory");  // buf cur^1 landed
    } else {
      asm volatile("s_waitcnt vmcnt(0)" ::: "memory");
    }
    __builtin_amdgcn_s_barrier();   // next buffer ready for all waves
    __builtin_amdgcn_sched_barrier(0);
    cur ^= 1;
  }
#undef DSTAGE
#undef DCOMPUTE

  // epilogue: score-scaled atomic scatter (fp32 adds, commutative; 2 adds/elem)
#pragma unroll
  for (int m = 0; m < 4; ++m) {
#pragma unroll
    for (int rg = 0; rg < 4; ++rg) {
      int row = wm * 64 + m * 16 + kq * 4 + rg;
      int ent = toks[row];
      if (ent >= 0) {
        int tokn = ent >> 1;
        float sc = sc2[tokn * 2 + (ent & 1)];
        float* dst = out + (size_t)tokn * D_DIM + col0 + wn * 32;
#pragma unroll
        for (int n = 0; n < 2; ++n)
          atomicAdd(&dst[n * 16 + lr], acc[m][n][rg] * sc);
      }
    }
  }
}

extern "C" void kernel_launch(void* const* d_in, const int* in_sizes, int n_in,
                              void* d_out, int out_size, void* d_ws, size_t ws_size,
                              hipStream_t stream) {
  const float* x  = (const float*)d_in[0];
  const float* Wg = (const float*)d_in[1];
  const float* W1 = (const float*)d_in[2];
  const float* W2 = (const float*)d_in[3];
  float* out = (float*)d_out;

  // workspace layout (~200.3 MiB total)
  char* ws = (char*)d_ws;
  size_t off = 0;
  u16* xb  = (u16*)(ws + off); off += (size_t)N_TOK * D_DIM * 2;          // 8 MiB
  u16* w1t = (u16*)(ws + off); off += (size_t)E_NUM * F_DIM * D_DIM * 2;  // 64 MiB
  u16* w2t = (u16*)(ws + off); off += (size_t)E_NUM * D_DIM * F_DIM * 2;  // 64 MiB
  u16* act = (u16*)(ws + off); off += (size_t)2 * N_TOK * F_DIM * 2;      // 64 MiB
  int* tok_list = (int*)(ws + off); off += (size_t)E_NUM * N_TOK * 4;     // 128 KiB
  float* sc2 = (float*)(ws + off); off += (size_t)N_TOK * 2 * 4;          // 32 KiB
  int2* choice = (int2*)(ws + off); off += (size_t)N_TOK * 8;             // 32 KiB
  int* cnt  = (int*)(ws + off); off += 128;
  int* base = (int*)(ws + off); off += 128;

  hipMemsetAsync(d_out, 0, (size_t)out_size * 4, stream);

  transpose_cvt2_kernel<<<dim3(16384), 256, 0, stream>>>(W1, W2, w1t, w2t);

  gate_kernel<<<N_TOK, 64, 0, stream>>>(x, Wg, xb, choice, sc2);
  route_kernel<<<E_NUM, 64, 0, stream>>>(choice, cnt, tok_list);
  prefix_kernel<<<1, 1, 0, stream>>>(cnt, base);

  up_gemm<<<dim3(8192), 512, 0, stream>>>(xb, w1t, cnt, base, tok_list, act);
  down_gemm<<<dim3(2048), 512, 0, stream>>>(act, w2t, cnt, base, tok_list, sc2, out);
}

// Round 20
// 322.685 us; speedup vs baseline: 1.1141x; 1.1141x over previous
//
#include <hip/hip_runtime.h>
#include <hip/hip_bf16.h>
#include <stdint.h>

// Problem constants (B=2, T=2048, D=1024, F=4096, E=8)
#define N_TOK 4096      // B*T
#define D_DIM 1024
#define F_DIM 4096
#define E_NUM 8

typedef unsigned short u16;
typedef __attribute__((ext_vector_type(8))) short short8;   // 8 bf16 (4 VGPRs)
typedef __attribute__((ext_vector_type(4))) float f32x4;

__device__ __forceinline__ u16 f2bf(float f) {
  union { float f; uint32_t u; } v; v.f = f;
  uint32_t u = v.u;
  uint32_t r = (u + 0x7FFFu + ((u >> 16) & 1u)) >> 16;
  return (u16)r;
}

__device__ __forceinline__ void gld_lds16(const u16* g, u16* l) {
  // async global->LDS, 16B per lane; LDS dest = wave-uniform base + lane*16
  __builtin_amdgcn_global_load_lds(
      (const __attribute__((address_space(1))) uint32_t*)g,
      (__attribute__((address_space(3))) uint32_t*)l, 16, 0, 0);
}

// ---- merged transpose+convert: W1 [E][D][F] -> w1t [E][F][D], W2 likewise ----
// One launch, 16384 blocks: [0,8192) = W1, [8192,16384) = W2. 64x64 tiles.
__global__ __launch_bounds__(256) void transpose_cvt2_kernel(
    const float* __restrict__ W1, const float* __restrict__ W2,
    u16* __restrict__ w1t, u16* __restrict__ w2t) {
  __shared__ u16 tile[64][72];   // pad 72: 144B row stride
  int bid = blockIdx.x;
  const float* src; u16* dst; int R, C, bx, by, e;
  if (bid < 8192) {
    int s = bid; bx = s & 63; by = (s >> 6) & 15; e = s >> 10;
    R = D_DIM; C = F_DIM;
    src = W1 + (size_t)e * R * C; dst = w1t + (size_t)e * R * C;
  } else {
    int s = bid - 8192; bx = s & 15; by = (s >> 4) & 63; e = s >> 10;
    R = F_DIM; C = D_DIM;
    src = W2 + (size_t)e * R * C; dst = w2t + (size_t)e * R * C;
  }
  int r0 = by * 64, c0 = bx * 64;
  int tid = threadIdx.x;
  int lr = tid & 15;    // 16 lanes cover 64 elems
  int rr = tid >> 4;    // 16 rows / pass
#pragma unroll
  for (int p = 0; p < 4; ++p) {
    int r = rr + p * 16;
    float4 v = *(const float4*)&src[(size_t)(r0 + r) * C + c0 + lr * 4];
    tile[lr * 4 + 0][r] = f2bf(v.x);
    tile[lr * 4 + 1][r] = f2bf(v.y);
    tile[lr * 4 + 2][r] = f2bf(v.z);
    tile[lr * 4 + 3][r] = f2bf(v.w);
  }
  __syncthreads();
#pragma unroll
  for (int p = 0; p < 4; ++p) {
    int c = rr + p * 16;
    ushort4 o = *(const ushort4*)&tile[c][lr * 4];
    *(ushort4*)&dst[(size_t)(c0 + c) * R + r0 + lr * 4] = o;
  }
}

// -------- gate: logits, top-2, softmax + fused x->bf16 convert (NO atomics) --------
// 4 tokens per block (4 waves, 1 token/wave) — 1024 blocks, Wg L1-amortized.
__global__ __launch_bounds__(256) void gate_kernel(
    const float* __restrict__ x, const float* __restrict__ Wg,
    u16* __restrict__ xb, int2* __restrict__ choice, float* __restrict__ sc2) {
  int n = blockIdx.x * 4 + (threadIdx.x >> 6);
  int l = threadIdx.x & 63;
  const float* xr = x + (size_t)n * D_DIM;
  u16* xbr = xb + (size_t)n * D_DIM;
  float acc[E_NUM];
#pragma unroll
  for (int e = 0; e < E_NUM; ++e) acc[e] = 0.f;
  for (int d = l; d < D_DIM; d += 64) {
    float xv = xr[d];
    xbr[d] = f2bf(xv);          // fused convert (coalesced 2B/lane)
#pragma unroll
    for (int e = 0; e < E_NUM; ++e) acc[e] += xv * Wg[e * D_DIM + d];
  }
#pragma unroll
  for (int e = 0; e < E_NUM; ++e) {
    float v = acc[e];
#pragma unroll
    for (int off = 32; off > 0; off >>= 1) v += __shfl_xor(v, off);
    acc[e] = v;
  }
  if (l == 0) {
    int i0 = 0; float m0 = acc[0];
#pragma unroll
    for (int e = 1; e < E_NUM; ++e) if (acc[e] > m0) { m0 = acc[e]; i0 = e; }
    int i1 = -1; float m1 = -INFINITY;
#pragma unroll
    for (int e = 0; e < E_NUM; ++e) if (e != i0 && acc[e] > m1) { m1 = acc[e]; i1 = e; }
    float z = __expf(m1 - m0);
    float s0 = 1.f / (1.f + z);
    sc2[n * 2 + 0] = s0;
    sc2[n * 2 + 1] = 1.f - s0;
    choice[n] = make_int2(i0, i1);
  }
}

// ---------------- route: deterministic ballot-prefix compaction ----------------
__global__ void route_kernel(const int2* __restrict__ choice, int* __restrict__ cnt,
                             int* __restrict__ tok_list) {
  int e = blockIdx.x;
  int l = threadIdx.x;  // 64
  unsigned long long below = (l == 0) ? 0ull : ((~0ull) >> (64 - l));
  int c = 0;
  for (int it = 0; it < N_TOK / 64; ++it) {
    int n = it * 64 + l;
    int2 ch = choice[n];
    unsigned long long b0 = __ballot(ch.x == e);
    if (ch.x == e) tok_list[e * N_TOK + c + __popcll(b0 & below)] = 2 * n;
    c += __popcll(b0);
    unsigned long long b1 = __ballot(ch.y == e);
    if (ch.y == e) tok_list[e * N_TOK + c + __popcll(b1 & below)] = 2 * n + 1;
    c += __popcll(b1);
  }
  if (l == 0) cnt[e] = c;
}

__global__ void prefix_kernel(const int* __restrict__ cnt, int* __restrict__ base) {
  if (threadIdx.x == 0) {
    int s = 0;
    for (int e = 0; e < E_NUM; ++e) { base[e] = s; s += cnt[e]; }
  }
}

// ---------------- up GEMM: act[be+i][f] = silu( x[tok_i] @ W1[e] ) ----------------
// r18 config (verified): 128x128, BK=32, 8 waves (2M x 4N, acc[4][2]), dbuf,
// counted vmcnt(2), raw barriers. Grid 8192 -> 4 blocks/CU. XCD-chunked q=1024.
__global__ __launch_bounds__(512) void up_gemm(
    const u16* __restrict__ xb, const u16* __restrict__ w1t,
    const int* __restrict__ cnt, const int* __restrict__ base,
    const int* __restrict__ tok_list, u16* __restrict__ act) {
  __shared__ u16 As[2][128 * 32];
  __shared__ u16 Bs[2][128 * 32];

  const int bid = blockIdx.x;
  const int orig = (bid & 7) * 1024 + (bid >> 3);   // bijective: 8192 % 8 == 0
  const int bx = orig & 31, by = (orig >> 5) & 31, e = orig >> 10;

  const int ce = cnt[e];
  const int row0 = by * 128;
  if (row0 >= ce) return;
  const int col0 = bx * 128;
  const int be = base[e];

  const int tid = threadIdx.x;
  const int wave = tid >> 6, lane = tid & 63;
  const int wm = wave >> 2, wn = wave & 3;          // 2M x 4N
  const int lr = lane & 15, kq = lane >> 4;

  const int rsA = wave * 16 + (lane >> 2);          // one 16-row segment per wave
  const int kb = (((lane & 3) ^ ((lane >> 3) & 3)) * 8);  // swizzled write k-offset
  const int kq8 = ((kq ^ ((lr >> 1) & 3)) * 8);           // swizzled read k-offset

  int ga = row0 + rsA;
  int e0 = (ga < ce) ? (tok_list[e * N_TOK + ga] & (2 * N_TOK - 1)) : 0;
  const u16* srcA = xb + (e0 >> 1) * D_DIM + kb;
  const u16* srcB = w1t + (size_t)(e * F_DIM + col0 + rsA) * D_DIM + kb;

  f32x4 acc[4][2];
#pragma unroll
  for (int m = 0; m < 4; ++m)
#pragma unroll
    for (int n = 0; n < 2; ++n) acc[m][n] = (f32x4){0.f, 0.f, 0.f, 0.f};

#define USTAGE(k0, b)                              \
  do {                                             \
    gld_lds16(srcA + (k0), &As[b][wave * 512]);    \
    gld_lds16(srcB + (k0), &Bs[b][wave * 512]);    \
  } while (0)

#define UCOMPUTE(b)                                                           \
  do {                                                                        \
    short8 a[4], bb[2];                                                       \
    _Pragma("unroll") for (int m = 0; m < 4; ++m)                             \
        a[m] = *(const short8*)&As[b][(wm * 64 + m * 16 + lr) * 32 + kq8];    \
    _Pragma("unroll") for (int n = 0; n < 2; ++n)                             \
        bb[n] = *(const short8*)&Bs[b][(wn * 32 + n * 16 + lr) * 32 + kq8];   \
    _Pragma("unroll") for (int m = 0; m < 4; ++m)                             \
        _Pragma("unroll") for (int n = 0; n < 2; ++n)                         \
            acc[m][n] = __builtin_amdgcn_mfma_f32_16x16x32_bf16(a[m], bb[n], acc[m][n], 0, 0, 0); \
  } while (0)

  const int NT = D_DIM / 32;   // 32 K-steps
  USTAGE(0, 0);
  USTAGE(32, 1);
  asm volatile("s_waitcnt vmcnt(2)" ::: "memory");
  __builtin_amdgcn_s_barrier();
  __builtin_amdgcn_sched_barrier(0);
  int cur = 0;
  for (int t = 0; t < NT; ++t) {
    UCOMPUTE(cur);
    __builtin_amdgcn_sched_barrier(0);
    __builtin_amdgcn_s_barrier();
    __builtin_amdgcn_sched_barrier(0);
    if (t + 2 < NT) {
      USTAGE((t + 2) * 32, cur);
      asm volatile("s_waitcnt vmcnt(2)" ::: "memory");
    } else {
      asm volatile("s_waitcnt vmcnt(0)" ::: "memory");
    }
    __builtin_amdgcn_s_barrier();
    __builtin_amdgcn_sched_barrier(0);
    cur ^= 1;
  }
#undef USTAGE
#undef UCOMPUTE

  // epilogue: silu (native exp) -> bf16 act
#pragma unroll
  for (int m = 0; m < 4; ++m) {
#pragma unroll
    for (int rg = 0; rg < 4; ++rg) {
      int row = wm * 64 + m * 16 + kq * 4 + rg;
      int i = row0 + row;
      if (i < ce) {
        u16* dst = act + (size_t)(be + i) * F_DIM + col0 + wn * 32;
#pragma unroll
        for (int n = 0; n < 2; ++n) {
          float v = acc[m][n][rg];
          float s = v / (1.f + __expf(-v));
          dst[n * 16 + lr] = f2bf(s);
        }
      }
    }
  }
}

// ---------------- down GEMM: out[tok] += score * ( act_row @ W2[e] ) ----------------
// r13 verified best (121 us): 8 waves, 128x128, BK=32, dbuf, counted vmcnt(2),
// raw barriers. Grid 2048 (8x * 32y * 8e), XCD-chunked q=256.
__global__ __launch_bounds__(512) void down_gemm(
    const u16* __restrict__ act, const u16* __restrict__ w2t,
    const int* __restrict__ cnt, const int* __restrict__ base,
    const int* __restrict__ tok_list, const float* __restrict__ sc2,
    float* __restrict__ out) {
  __shared__ u16 As[2][128 * 32];
  __shared__ u16 Bs[2][128 * 32];
  __shared__ int toks[128];

  const int bid = blockIdx.x;
  const int orig = (bid & 7) * 256 + (bid >> 3);    // bijective: 2048 % 8 == 0
  const int bx = orig & 7, by = (orig >> 3) & 31, e = orig >> 8;

  const int ce = cnt[e];
  const int row0 = by * 128;
  if (row0 >= ce) return;
  const int col0 = bx * 128;
  const int be = base[e];

  const int tid = threadIdx.x;
  const int wave = tid >> 6, lane = tid & 63;
  const int wm = wave >> 2, wn = wave & 3;          // 2M x 4N
  const int lr = lane & 15, kq = lane >> 4;

  if (tid < 128) {
    int i = row0 + tid;
    toks[tid] = (i < ce) ? tok_list[e * N_TOK + i] : -1;
  }
  __syncthreads();   // toks visible before raw-barrier loop

  const int rsA = wave * 16 + (lane >> 2);          // one 16-row segment per wave
  const int kb = (((lane & 3) ^ ((lane >> 3) & 3)) * 8);  // swizzled write k-offset
  const int kq8 = ((kq ^ ((lr >> 1) & 3)) * 8);           // swizzled read k-offset

  int ra = min(be + row0 + rsA, 2 * N_TOK - 1);     // clamp inside act buffer
  const u16* srcA = act + (size_t)ra * F_DIM + kb;
  const u16* srcB = w2t + (size_t)(e * D_DIM + col0 + rsA) * F_DIM + kb;

  f32x4 acc[4][2];
#pragma unroll
  for (int m = 0; m < 4; ++m)
#pragma unroll
    for (int n = 0; n < 2; ++n) acc[m][n] = (f32x4){0.f, 0.f, 0.f, 0.f};

#define DSTAGE(k0, b)                              \
  do {                                             \
    gld_lds16(srcA + (k0), &As[b][wave * 512]);    \
    gld_lds16(srcB + (k0), &Bs[b][wave * 512]);    \
  } while (0)

#define DCOMPUTE(b)                                                           \
  do {                                                                        \
    short8 a[4], bb[2];                                                       \
    _Pragma("unroll") for (int m = 0; m < 4; ++m)                             \
        a[m] = *(const short8*)&As[b][(wm * 64 + m * 16 + lr) * 32 + kq8];    \
    _Pragma("unroll") for (int n = 0; n < 2; ++n)                             \
        bb[n] = *(const short8*)&Bs[b][(wn * 32 + n * 16 + lr) * 32 + kq8];   \
    _Pragma("unroll") for (int m = 0; m < 4; ++m)                             \
        _Pragma("unroll") for (int n = 0; n < 2; ++n)                         \
            acc[m][n] = __builtin_amdgcn_mfma_f32_16x16x32_bf16(a[m], bb[n], acc[m][n], 0, 0, 0); \
  } while (0)

  const int NT = F_DIM / 32;   // 128 K-steps
  DSTAGE(0, 0);
  DSTAGE(32, 1);
  asm volatile("s_waitcnt vmcnt(2)" ::: "memory");   // buf0 landed (per-wave)
  __builtin_amdgcn_s_barrier();
  __builtin_amdgcn_sched_barrier(0);
  int cur = 0;
  for (int t = 0; t < NT; ++t) {
    DCOMPUTE(cur);
    __builtin_amdgcn_sched_barrier(0);
    __builtin_amdgcn_s_barrier();   // all readers done with buf cur
    __builtin_amdgcn_sched_barrier(0);
    if (t + 2 < NT) {
      DSTAGE((t + 2) * 32, cur);
      asm volatile("s_waitcnt vmcnt(2)" ::: "memory");  // buf cur^1 landed
    } else {
      asm volatile("s_waitcnt vmcnt(0)" ::: "memory");
    }
    __builtin_amdgcn_s_barrier();   // next buffer ready for all waves
    __builtin_amdgcn_sched_barrier(0);
    cur ^= 1;
  }
#undef DSTAGE
#undef DCOMPUTE

  // epilogue: score-scaled atomic scatter (fp32 adds, commutative; 2 adds/elem)
#pragma unroll
  for (int m = 0; m < 4; ++m) {
#pragma unroll
    for (int rg = 0; rg < 4; ++rg) {
      int row = wm * 64 + m * 16 + kq * 4 + rg;
      int ent = toks[row];
      if (ent >= 0) {
        int tokn = ent >> 1;
        float sc = sc2[tokn * 2 + (ent & 1)];
        float* dst = out + (size_t)tokn * D_DIM + col0 + wn * 32;
#pragma unroll
        for (int n = 0; n < 2; ++n)
          atomicAdd(&dst[n * 16 + lr], acc[m][n][rg] * sc);
      }
    }
  }
}

extern "C" void kernel_launch(void* const* d_in, const int* in_sizes, int n_in,
                              void* d_out, int out_size, void* d_ws, size_t ws_size,
                              hipStream_t stream) {
  const float* x  = (const float*)d_in[0];
  const float* Wg = (const float*)d_in[1];
  const float* W1 = (const float*)d_in[2];
  const float* W2 = (const float*)d_in[3];
  float* out = (float*)d_out;

  // workspace layout (~200.3 MiB total)
  char* ws = (char*)d_ws;
  size_t off = 0;
  u16* xb  = (u16*)(ws + off); off += (size_t)N_TOK * D_DIM * 2;          // 8 MiB
  u16* w1t = (u16*)(ws + off); off += (size_t)E_NUM * F_DIM * D_DIM * 2;  // 64 MiB
  u16* w2t = (u16*)(ws + off); off += (size_t)E_NUM * D_DIM * F_DIM * 2;  // 64 MiB
  u16* act = (u16*)(ws + off); off += (size_t)2 * N_TOK * F_DIM * 2;      // 64 MiB
  int* tok_list = (int*)(ws + off); off += (size_t)E_NUM * N_TOK * 4;     // 128 KiB
  float* sc2 = (float*)(ws + off); off += (size_t)N_TOK * 2 * 4;          // 32 KiB
  int2* choice = (int2*)(ws + off); off += (size_t)N_TOK * 8;             // 32 KiB
  int* cnt  = (int*)(ws + off); off += 128;
  int* base = (int*)(ws + off); off += 128;

  hipMemsetAsync(d_out, 0, (size_t)out_size * 4, stream);

  transpose_cvt2_kernel<<<dim3(16384), 256, 0, stream>>>(W1, W2, w1t, w2t);

  gate_kernel<<<dim3(N_TOK / 4), 256, 0, stream>>>(x, Wg, xb, choice, sc2);
  route_kernel<<<E_NUM, 64, 0, stream>>>(choice, cnt, tok_list);
  prefix_kernel<<<1, 1, 0, stream>>>(cnt, base);

  up_gemm<<<dim3(8192), 512, 0, stream>>>(xb, w1t, cnt, base, tok_list, act);
  down_gemm<<<dim3(2048), 512, 0, stream>>>(act, w2t, cnt, base, tok_list, sc2, out);
}

// Round 21
// 320.167 us; speedup vs baseline: 1.1229x; 1.0079x over previous
//
#include <hip/hip_runtime.h>
#include <hip/hip_bf16.h>
#include <stdint.h>

// Problem constants (B=2, T=2048, D=1024, F=4096, E=8)
#define N_TOK 4096      // B*T
#define D_DIM 1024
#define F_DIM 4096
#define E_NUM 8

typedef unsigned short u16;
typedef __attribute__((ext_vector_type(8))) short short8;   // 8 bf16 (4 VGPRs)
typedef __attribute__((ext_vector_type(4))) float f32x4;

__device__ __forceinline__ u16 f2bf(float f) {
  union { float f; uint32_t u; } v; v.f = f;
  uint32_t u = v.u;
  uint32_t r = (u + 0x7FFFu + ((u >> 16) & 1u)) >> 16;
  return (u16)r;
}

__device__ __forceinline__ void gld_lds16(const u16* g, u16* l) {
  // async global->LDS, 16B per lane; LDS dest = wave-uniform base + lane*16
  __builtin_amdgcn_global_load_lds(
      (const __attribute__((address_space(1))) uint32_t*)g,
      (__attribute__((address_space(3))) uint32_t*)l, 16, 0, 0);
}

// ==== fused prep: gate (blocks 0..1023) + W1/W2 transpose (1024..17407) ====
// Gate and transposes are data-independent; merging hides gate's ~13 us under
// the transpose's HBM-bound shadow. All blocks 256 threads.
__global__ __launch_bounds__(256) void prep_kernel(
    const float* __restrict__ x, const float* __restrict__ Wg,
    const float* __restrict__ W1, const float* __restrict__ W2,
    u16* __restrict__ xb, int2* __restrict__ choice, float* __restrict__ sc2,
    u16* __restrict__ w1t, u16* __restrict__ w2t) {
  int bid = blockIdx.x;
  if (bid < 1024) {
    // ---- gate: 4 tokens per block (1 token/wave) + fused x->bf16 convert ----
    int n = bid * 4 + (threadIdx.x >> 6);
    int l = threadIdx.x & 63;
    const float* xr = x + (size_t)n * D_DIM;
    u16* xbr = xb + (size_t)n * D_DIM;
    float acc[E_NUM];
#pragma unroll
    for (int e = 0; e < E_NUM; ++e) acc[e] = 0.f;
    for (int d = l; d < D_DIM; d += 64) {
      float xv = xr[d];
      xbr[d] = f2bf(xv);
#pragma unroll
      for (int e = 0; e < E_NUM; ++e) acc[e] += xv * Wg[e * D_DIM + d];
    }
#pragma unroll
    for (int e = 0; e < E_NUM; ++e) {
      float v = acc[e];
#pragma unroll
      for (int off = 32; off > 0; off >>= 1) v += __shfl_xor(v, off);
      acc[e] = v;
    }
    if (l == 0) {
      int i0 = 0; float m0 = acc[0];
#pragma unroll
      for (int e = 1; e < E_NUM; ++e) if (acc[e] > m0) { m0 = acc[e]; i0 = e; }
      int i1 = -1; float m1 = -INFINITY;
#pragma unroll
      for (int e = 0; e < E_NUM; ++e) if (e != i0 && acc[e] > m1) { m1 = acc[e]; i1 = e; }
      float z = __expf(m1 - m0);
      float s0 = 1.f / (1.f + z);
      sc2[n * 2 + 0] = s0;
      sc2[n * 2 + 1] = 1.f - s0;
      choice[n] = make_int2(i0, i1);
    }
    return;
  }
  // ---- transpose+convert: 64x64 tiles ----
  __shared__ u16 tile[64][72];   // pad 72: 144B row stride
  const float* src; u16* dst; int R, C, bx, by, e;
  if (bid < 1024 + 8192) {
    int s = bid - 1024; bx = s & 63; by = (s >> 6) & 15; e = s >> 10;
    R = D_DIM; C = F_DIM;
    src = W1 + (size_t)e * R * C; dst = w1t + (size_t)e * R * C;
  } else {
    int s = bid - 1024 - 8192; bx = s & 15; by = (s >> 4) & 63; e = s >> 10;
    R = F_DIM; C = D_DIM;
    src = W2 + (size_t)e * R * C; dst = w2t + (size_t)e * R * C;
  }
  int r0 = by * 64, c0 = bx * 64;
  int tid = threadIdx.x;
  int lr = tid & 15;    // 16 lanes cover 64 elems
  int rr = tid >> 4;    // 16 rows / pass
#pragma unroll
  for (int p = 0; p < 4; ++p) {
    int r = rr + p * 16;
    float4 v = *(const float4*)&src[(size_t)(r0 + r) * C + c0 + lr * 4];
    tile[lr * 4 + 0][r] = f2bf(v.x);
    tile[lr * 4 + 1][r] = f2bf(v.y);
    tile[lr * 4 + 2][r] = f2bf(v.z);
    tile[lr * 4 + 3][r] = f2bf(v.w);
  }
  __syncthreads();
#pragma unroll
  for (int p = 0; p < 4; ++p) {
    int c = rr + p * 16;
    ushort4 o = *(const ushort4*)&tile[c][lr * 4];
    *(ushort4*)&dst[(size_t)(c0 + c) * R + r0 + lr * 4] = o;
  }
}

// ---------------- route: deterministic ballot-prefix compaction ----------------
__global__ void route_kernel(const int2* __restrict__ choice, int* __restrict__ cnt,
                             int* __restrict__ tok_list) {
  int e = blockIdx.x;
  int l = threadIdx.x;  // 64
  unsigned long long below = (l == 0) ? 0ull : ((~0ull) >> (64 - l));
  int c = 0;
  for (int it = 0; it < N_TOK / 64; ++it) {
    int n = it * 64 + l;
    int2 ch = choice[n];
    unsigned long long b0 = __ballot(ch.x == e);
    if (ch.x == e) tok_list[e * N_TOK + c + __popcll(b0 & below)] = 2 * n;
    c += __popcll(b0);
    unsigned long long b1 = __ballot(ch.y == e);
    if (ch.y == e) tok_list[e * N_TOK + c + __popcll(b1 & below)] = 2 * n + 1;
    c += __popcll(b1);
  }
  if (l == 0) cnt[e] = c;
}

__global__ void prefix_kernel(const int* __restrict__ cnt, int* __restrict__ base) {
  if (threadIdx.x == 0) {
    int s = 0;
    for (int e = 0; e < E_NUM; ++e) { base[e] = s; s += cnt[e]; }
  }
}

// ---------------- up GEMM: act[be+i][f] = silu( x[tok_i] @ W1[e] ) ----------------
// r18 config (verified): 128x128, BK=32, 8 waves (2M x 4N, acc[4][2]), dbuf,
// counted vmcnt(2), raw barriers. Grid 8192 -> 4 blocks/CU. XCD-chunked q=1024.
__global__ __launch_bounds__(512) void up_gemm(
    const u16* __restrict__ xb, const u16* __restrict__ w1t,
    const int* __restrict__ cnt, const int* __restrict__ base,
    const int* __restrict__ tok_list, u16* __restrict__ act) {
  __shared__ u16 As[2][128 * 32];
  __shared__ u16 Bs[2][128 * 32];

  const int bid = blockIdx.x;
  const int orig = (bid & 7) * 1024 + (bid >> 3);   // bijective: 8192 % 8 == 0
  const int bx = orig & 31, by = (orig >> 5) & 31, e = orig >> 10;

  const int ce = cnt[e];
  const int row0 = by * 128;
  if (row0 >= ce) return;
  const int col0 = bx * 128;
  const int be = base[e];

  const int tid = threadIdx.x;
  const int wave = tid >> 6, lane = tid & 63;
  const int wm = wave >> 2, wn = wave & 3;          // 2M x 4N
  const int lr = lane & 15, kq = lane >> 4;

  const int rsA = wave * 16 + (lane >> 2);          // one 16-row segment per wave
  const int kb = (((lane & 3) ^ ((lane >> 3) & 3)) * 8);  // swizzled write k-offset
  const int kq8 = ((kq ^ ((lr >> 1) & 3)) * 8);           // swizzled read k-offset

  int ga = row0 + rsA;
  int e0 = (ga < ce) ? (tok_list[e * N_TOK + ga] & (2 * N_TOK - 1)) : 0;
  const u16* srcA = xb + (e0 >> 1) * D_DIM + kb;
  const u16* srcB = w1t + (size_t)(e * F_DIM + col0 + rsA) * D_DIM + kb;

  f32x4 acc[4][2];
#pragma unroll
  for (int m = 0; m < 4; ++m)
#pragma unroll
    for (int n = 0; n < 2; ++n) acc[m][n] = (f32x4){0.f, 0.f, 0.f, 0.f};

#define USTAGE(k0, b)                              \
  do {                                             \
    gld_lds16(srcA + (k0), &As[b][wave * 512]);    \
    gld_lds16(srcB + (k0), &Bs[b][wave * 512]);    \
  } while (0)

#define UCOMPUTE(b)                                                           \
  do {                                                                        \
    short8 a[4], bb[2];                                                       \
    _Pragma("unroll") for (int m = 0; m < 4; ++m)                             \
        a[m] = *(const short8*)&As[b][(wm * 64 + m * 16 + lr) * 32 + kq8];    \
    _Pragma("unroll") for (int n = 0; n < 2; ++n)                             \
        bb[n] = *(const short8*)&Bs[b][(wn * 32 + n * 16 + lr) * 32 + kq8];   \
    _Pragma("unroll") for (int m = 0; m < 4; ++m)                             \
        _Pragma("unroll") for (int n = 0; n < 2; ++n)                         \
            acc[m][n] = __builtin_amdgcn_mfma_f32_16x16x32_bf16(a[m], bb[n], acc[m][n], 0, 0, 0); \
  } while (0)

  const int NT = D_DIM / 32;   // 32 K-steps
  USTAGE(0, 0);
  USTAGE(32, 1);
  asm volatile("s_waitcnt vmcnt(2)" ::: "memory");
  __builtin_amdgcn_s_barrier();
  __builtin_amdgcn_sched_barrier(0);
  int cur = 0;
  for (int t = 0; t < NT; ++t) {
    UCOMPUTE(cur);
    __builtin_amdgcn_sched_barrier(0);
    __builtin_amdgcn_s_barrier();
    __builtin_amdgcn_sched_barrier(0);
    if (t + 2 < NT) {
      USTAGE((t + 2) * 32, cur);
      asm volatile("s_waitcnt vmcnt(2)" ::: "memory");
    } else {
      asm volatile("s_waitcnt vmcnt(0)" ::: "memory");
    }
    __builtin_amdgcn_s_barrier();
    __builtin_amdgcn_sched_barrier(0);
    cur ^= 1;
  }
#undef USTAGE
#undef UCOMPUTE

  // epilogue: silu (native exp) -> bf16 act
#pragma unroll
  for (int m = 0; m < 4; ++m) {
#pragma unroll
    for (int rg = 0; rg < 4; ++rg) {
      int row = wm * 64 + m * 16 + kq * 4 + rg;
      int i = row0 + row;
      if (i < ce) {
        u16* dst = act + (size_t)(be + i) * F_DIM + col0 + wn * 32;
#pragma unroll
        for (int n = 0; n < 2; ++n) {
          float v = acc[m][n][rg];
          float s = v / (1.f + __expf(-v));
          dst[n * 16 + lr] = f2bf(s);
        }
      }
    }
  }
}

// ---------------- down GEMM: out[tok] += score * ( act_row @ W2[e] ) ----------------
// r13 verified best (121 us): 8 waves, 128x128, BK=32, dbuf, counted vmcnt(2),
// raw barriers. Grid 2048 (8x * 32y * 8e), XCD-chunked q=256.
__global__ __launch_bounds__(512) void down_gemm(
    const u16* __restrict__ act, const u16* __restrict__ w2t,
    const int* __restrict__ cnt, const int* __restrict__ base,
    const int* __restrict__ tok_list, const float* __restrict__ sc2,
    float* __restrict__ out) {
  __shared__ u16 As[2][128 * 32];
  __shared__ u16 Bs[2][128 * 32];
  __shared__ int toks[128];

  const int bid = blockIdx.x;
  const int orig = (bid & 7) * 256 + (bid >> 3);    // bijective: 2048 % 8 == 0
  const int bx = orig & 7, by = (orig >> 3) & 31, e = orig >> 8;

  const int ce = cnt[e];
  const int row0 = by * 128;
  if (row0 >= ce) return;
  const int col0 = bx * 128;
  const int be = base[e];

  const int tid = threadIdx.x;
  const int wave = tid >> 6, lane = tid & 63;
  const int wm = wave >> 2, wn = wave & 3;          // 2M x 4N
  const int lr = lane & 15, kq = lane >> 4;

  if (tid < 128) {
    int i = row0 + tid;
    toks[tid] = (i < ce) ? tok_list[e * N_TOK + i] : -1;
  }
  __syncthreads();   // toks visible before raw-barrier loop

  const int rsA = wave * 16 + (lane >> 2);          // one 16-row segment per wave
  const int kb = (((lane & 3) ^ ((lane >> 3) & 3)) * 8);  // swizzled write k-offset
  const int kq8 = ((kq ^ ((lr >> 1) & 3)) * 8);           // swizzled read k-offset

  int ra = min(be + row0 + rsA, 2 * N_TOK - 1);     // clamp inside act buffer
  const u16* srcA = act + (size_t)ra * F_DIM + kb;
  const u16* srcB = w2t + (size_t)(e * D_DIM + col0 + rsA) * F_DIM + kb;

  f32x4 acc[4][2];
#pragma unroll
  for (int m = 0; m < 4; ++m)
#pragma unroll
    for (int n = 0; n < 2; ++n) acc[m][n] = (f32x4){0.f, 0.f, 0.f, 0.f};

#define DSTAGE(k0, b)                              \
  do {                                             \
    gld_lds16(srcA + (k0), &As[b][wave * 512]);    \
    gld_lds16(srcB + (k0), &Bs[b][wave * 512]);    \
  } while (0)

#define DCOMPUTE(b)                                                           \
  do {                                                                        \
    short8 a[4], bb[2];                                                       \
    _Pragma("unroll") for (int m = 0; m < 4; ++m)                             \
        a[m] = *(const short8*)&As[b][(wm * 64 + m * 16 + lr) * 32 + kq8];    \
    _Pragma("unroll") for (int n = 0; n < 2; ++n)                             \
        bb[n] = *(const short8*)&Bs[b][(wn * 32 + n * 16 + lr) * 32 + kq8];   \
    _Pragma("unroll") for (int m = 0; m < 4; ++m)                             \
        _Pragma("unroll") for (int n = 0; n < 2; ++n)                         \
            acc[m][n] = __builtin_amdgcn_mfma_f32_16x16x32_bf16(a[m], bb[n], acc[m][n], 0, 0, 0); \
  } while (0)

  const int NT = F_DIM / 32;   // 128 K-steps
  DSTAGE(0, 0);
  DSTAGE(32, 1);
  asm volatile("s_waitcnt vmcnt(2)" ::: "memory");   // buf0 landed (per-wave)
  __builtin_amdgcn_s_barrier();
  __builtin_amdgcn_sched_barrier(0);
  int cur = 0;
  for (int t = 0; t < NT; ++t) {
    DCOMPUTE(cur);
    __builtin_amdgcn_sched_barrier(0);
    __builtin_amdgcn_s_barrier();   // all readers done with buf cur
    __builtin_amdgcn_sched_barrier(0);
    if (t + 2 < NT) {
      DSTAGE((t + 2) * 32, cur);
      asm volatile("s_waitcnt vmcnt(2)" ::: "memory");  // buf cur^1 landed
    } else {
      asm volatile("s_waitcnt vmcnt(0)" ::: "memory");
    }
    __builtin_amdgcn_s_barrier();   // next buffer ready for all waves
    __builtin_amdgcn_sched_barrier(0);
    cur ^= 1;
  }
#undef DSTAGE
#undef DCOMPUTE

  // epilogue: score-scaled atomic scatter (fp32 adds, commutative; 2 adds/elem)
#pragma unroll
  for (int m = 0; m < 4; ++m) {
#pragma unroll
    for (int rg = 0; rg < 4; ++rg) {
      int row = wm * 64 + m * 16 + kq * 4 + rg;
      int ent = toks[row];
      if (ent >= 0) {
        int tokn = ent >> 1;
        float sc = sc2[tokn * 2 + (ent & 1)];
        float* dst = out + (size_t)tokn * D_DIM + col0 + wn * 32;
#pragma unroll
        for (int n = 0; n < 2; ++n)
          atomicAdd(&dst[n * 16 + lr], acc[m][n][rg] * sc);
      }
    }
  }
}

extern "C" void kernel_launch(void* const* d_in, const int* in_sizes, int n_in,
                              void* d_out, int out_size, void* d_ws, size_t ws_size,
                              hipStream_t stream) {
  const float* x  = (const float*)d_in[0];
  const float* Wg = (const float*)d_in[1];
  const float* W1 = (const float*)d_in[2];
  const float* W2 = (const float*)d_in[3];
  float* out = (float*)d_out;

  // workspace layout (~200.3 MiB total)
  char* ws = (char*)d_ws;
  size_t off = 0;
  u16* xb  = (u16*)(ws + off); off += (size_t)N_TOK * D_DIM * 2;          // 8 MiB
  u16* w1t = (u16*)(ws + off); off += (size_t)E_NUM * F_DIM * D_DIM * 2;  // 64 MiB
  u16* w2t = (u16*)(ws + off); off += (size_t)E_NUM * D_DIM * F_DIM * 2;  // 64 MiB
  u16* act = (u16*)(ws + off); off += (size_t)2 * N_TOK * F_DIM * 2;      // 64 MiB
  int* tok_list = (int*)(ws + off); off += (size_t)E_NUM * N_TOK * 4;     // 128 KiB
  float* sc2 = (float*)(ws + off); off += (size_t)N_TOK * 2 * 4;          // 32 KiB
  int2* choice = (int2*)(ws + off); off += (size_t)N_TOK * 8;             // 32 KiB
  int* cnt  = (int*)(ws + off); off += 128;
  int* base = (int*)(ws + off); off += 128;

  hipMemsetAsync(d_out, 0, (size_t)out_size * 4, stream);

  prep_kernel<<<dim3(1024 + 16384), 256, 0, stream>>>(x, Wg, W1, W2, xb, choice,
                                                      sc2, w1t, w2t);
  route_kernel<<<E_NUM, 64, 0, stream>>>(choice, cnt, tok_list);
  prefix_kernel<<<1, 1, 0, stream>>>(cnt, base);

  up_gemm<<<dim3(8192), 512, 0, stream>>>(xb, w1t, cnt, base, tok_list, act);
  down_gemm<<<dim3(2048), 512, 0, stream>>>(act, w2t, cnt, base, tok_list, sc2, out);
}